// Round 7
// baseline (69.545 us; speedup 1.0000x reference)
//
#include <hip/hip_runtime.h>

#define N_TASKS 16
#define LMAX 64
#define BLOCK 256
#define ITERS 32
#define ROWS_PER_BLOCK 512   // 32 chunks x 16 consecutive rows

typedef float f32x4 __attribute__((ext_vector_type(4)));
typedef float f32x2 __attribute__((ext_vector_type(2)));

// Hot kernel: requires total4 == gridDim.x * BLOCK * ITERS (exact cover).
// Store order is IDENTICAL to the proven grid-stride kernel (R5); only the
// per-iteration task_id/input gathers are replaced by one-time LDS staging.
__global__ __launch_bounds__(BLOCK) void MEWA_exact_kernel(
    const float* __restrict__ input,      // [B]
    const int*   __restrict__ task_ids,   // [B]
    const float* __restrict__ offsets,    // [N_TASKS*LMAX]
    const float* __restrict__ disc,       // [N_TASKS*LMAX]
    const int*   __restrict__ lengths,    // [N_TASKS]
    f32x4*       __restrict__ out)        // [B*16]
{
    __shared__ alignas(16) float s_tab[N_TASKS * 128];  // [t][0..63]=m, [64..127]=m*o
    __shared__ alignas(8)  f32x2 s_row[ROWS_PER_BLOCK]; // {x, bitcast(task)}

    const int tid          = threadIdx.x;
    const int chunk_stride = gridDim.x * 16;            // rows between iterations
    const int row0         = blockIdx.x * 16;

    for (int i = tid; i < N_TASKS * LMAX; i += BLOCK) {
        int t = i >> 6, k = i & (LMAX - 1);
        float m = (k < lengths[t]) ? disc[i] : 0.0f;
        s_tab[t * 128 + k]      = m;
        s_tab[t * 128 + 64 + k] = m * offsets[i];
    }
    // Stage the 512 rows this block will touch: chunk c = i>>4, lane j = i&15.
    for (int i = tid; i < ROWS_PER_BLOCK; i += BLOCK) {
        int r = row0 + (i & 15) + (i >> 4) * chunk_stride;
        f32x2 v;
        v.x = input[r];
        v.y = __int_as_float(task_ids[r]);
        s_row[i] = v;
    }
    __syncthreads();

    const int  k4     = tid & 15;
    const int  lg     = tid >> 4;                       // lane group = row within chunk
    const long stride = (long)gridDim.x * BLOCK;        // float4s per iteration step
    const long gbase  = (long)blockIdx.x * BLOCK + tid;

    #pragma unroll
    for (int it = 0; it < ITERS; ++it) {
        f32x2 rv = s_row[it * 16 + lg];                 // ds_read_b64 imm, 16-lane broadcast
        float x  = rv.x;
        int   t  = __float_as_int(rv.y);
        const float* base = &s_tab[t * 128 + (k4 << 2)];
        f32x4 mv = *(const f32x4*)(base);               // ds_read_b128
        f32x4 pv = *(const f32x4*)(base + 64);          // ds_read_b128 offset:256
        f32x4 r;
        r.x = fmaf(mv.x, x, pv.x);
        r.y = fmaf(mv.y, x, pv.y);
        r.z = fmaf(mv.z, x, pv.z);
        r.w = fmaf(mv.w, x, pv.w);
        __builtin_nontemporal_store(r, &out[gbase + it * stride]);  // lane-dense 1KB/wave
    }
}

// Fallback (any size): the R5 kernel verbatim.
__global__ __launch_bounds__(BLOCK) void MEWA_generic_kernel(
    const float* __restrict__ input, const int* __restrict__ task_ids,
    const float* __restrict__ offsets, const float* __restrict__ disc,
    const int* __restrict__ lengths, f32x4* __restrict__ out, int total4)
{
    __shared__ alignas(16) float s_tab[N_TASKS * 128];
    for (int i = threadIdx.x; i < N_TASKS * LMAX; i += BLOCK) {
        int t = i >> 6, k = i & (LMAX - 1);
        float m = (k < lengths[t]) ? disc[i] : 0.0f;
        s_tab[t * 128 + k]      = m;
        s_tab[t * 128 + 64 + k] = m * offsets[i];
    }
    __syncthreads();
    const int stride = gridDim.x * blockDim.x;
    int g = blockIdx.x * blockDim.x + threadIdx.x;
    if (g >= total4) return;
    int   t_cur = task_ids[g >> 4];
    float x_cur = input[g >> 4];
    for (; g < total4; g += stride) {
        int gn = g + stride;
        int rown = (gn < total4 ? gn : g) >> 4;
        int t_nxt = task_ids[rown];
        float x_nxt = input[rown];
        int k4 = g & 15;
        const float* base = &s_tab[t_cur * 128 + (k4 << 2)];
        f32x4 mv = *(const f32x4*)(base);
        f32x4 pv = *(const f32x4*)(base + 64);
        f32x4 r;
        r.x = fmaf(mv.x, x_cur, pv.x);
        r.y = fmaf(mv.y, x_cur, pv.y);
        r.z = fmaf(mv.z, x_cur, pv.z);
        r.w = fmaf(mv.w, x_cur, pv.w);
        __builtin_nontemporal_store(r, &out[g]);
        t_cur = t_nxt;
        x_cur = x_nxt;
    }
}

extern "C" void kernel_launch(void* const* d_in, const int* in_sizes, int n_in,
                              void* d_out, int out_size, void* d_ws, size_t ws_size,
                              hipStream_t stream) {
    const float* input    = (const float*)d_in[0];
    const int*   task_ids = (const int*)d_in[1];
    const float* offsets  = (const float*)d_in[2];
    const float* disc     = (const float*)d_in[3];
    const int*   lengths  = (const int*)d_in[4];
    f32x4*       out      = (f32x4*)d_out;

    int total4 = out_size / 4;                    // B * 16
    int grid   = total4 / (BLOCK * ITERS);        // 2048 for B=1M

    if (grid >= 1 && grid * BLOCK * ITERS == total4) {
        MEWA_exact_kernel<<<grid, BLOCK, 0, stream>>>(
            input, task_ids, offsets, disc, lengths, out);
    } else {
        int g2 = (total4 + BLOCK - 1) / BLOCK;
        if (g2 > 2048) g2 = 2048;
        MEWA_generic_kernel<<<g2, BLOCK, 0, stream>>>(
            input, task_ids, offsets, disc, lengths, out, total4);
    }
}

// Round 8
// 52.516 us; speedup vs baseline: 1.3243x; 1.3243x over previous
//
#include <hip/hip_runtime.h>

#define N_TASKS 16
#define LMAX 64
#define TSTRIDE 136  // dwords per task row; 136%32=8 -> task-dependent bank offset 8t,
                     // spreads the 4 lane-groups across different bank sets.
                     // 136*4=544B keeps 16B alignment; p-section still at +64 dwords.

typedef float f32x4 __attribute__((ext_vector_type(4)));

__global__ __launch_bounds__(256) void MultiElementWiseAffine_kernel(
    const float* __restrict__ input,      // [B]
    const int*   __restrict__ task_ids,   // [B]
    const float* __restrict__ offsets,    // [N_TASKS*LMAX]
    const float* __restrict__ disc,       // [N_TASKS*LMAX]
    const int*   __restrict__ lengths,    // [N_TASKS]
    f32x4*       __restrict__ out,        // [B*16] float4 view of [B][64]
    int total4)                           // B*16
{
    // Per-task: [t*136 + 0..63] = masked disc (m), [t*136 + 64..127] = m*offset.
    __shared__ alignas(16) float s_tab[N_TASKS * TSTRIDE];

    for (int i = threadIdx.x; i < N_TASKS * LMAX; i += blockDim.x) {
        int t = i >> 6;          // task
        int k = i & (LMAX - 1);  // threshold index
        float m = (k < lengths[t]) ? disc[i] : 0.0f;
        s_tab[t * TSTRIDE + k]      = m;
        s_tab[t * TSTRIDE + 64 + k] = m * offsets[i];
    }
    __syncthreads();

    const int stride = gridDim.x * blockDim.x;
    int g = blockIdx.x * blockDim.x + threadIdx.x;
    if (g >= total4) return;

    // 2-stage pipeline: prefetch next iteration's row data.
    int   t_cur = task_ids[g >> 4];
    float x_cur = input[g >> 4];

    for (; g < total4; g += stride) {
        int gn      = g + stride;
        int rown    = (gn < total4 ? gn : g) >> 4;
        int t_nxt   = task_ids[rown];
        float x_nxt = input[rown];

        int k4 = g & 15;
        const float* base = &s_tab[t_cur * TSTRIDE + (k4 << 2)];
        f32x4 mv = *(const f32x4*)(base);       // ds_read_b128
        f32x4 pv = *(const f32x4*)(base + 64);  // ds_read_b128 offset:256
        f32x4 r;
        r.x = fmaf(mv.x, x_cur, pv.x);
        r.y = fmaf(mv.y, x_cur, pv.y);
        r.z = fmaf(mv.z, x_cur, pv.z);
        r.w = fmaf(mv.w, x_cur, pv.w);
        // Lane-dense (lane i -> base+16B*i), grid-stride walk, non-temporal.
        __builtin_nontemporal_store(r, &out[g]);

        t_cur = t_nxt;
        x_cur = x_nxt;
    }
}

extern "C" void kernel_launch(void* const* d_in, const int* in_sizes, int n_in,
                              void* d_out, int out_size, void* d_ws, size_t ws_size,
                              hipStream_t stream) {
    const float* input    = (const float*)d_in[0];
    const int*   task_ids = (const int*)d_in[1];
    const float* offsets  = (const float*)d_in[2];
    const float* disc     = (const float*)d_in[3];
    const int*   lengths  = (const int*)d_in[4];
    f32x4*       out      = (f32x4*)d_out;

    int total4 = out_size / 4;           // B * 16
    int block  = 256;
    int grid   = 2048;                   // 8 blocks/CU, 32 iters/thread

    MultiElementWiseAffine_kernel<<<grid, block, 0, stream>>>(
        input, task_ids, offsets, disc, lengths, out, total4);
}